// Round 3
// baseline (344.923 us; speedup 1.0000x reference)
//
#include <hip/hip_runtime.h>

// Problem constants: B=8, N=1024, C=64, O=64, K+1=4
#define EPS_Q 1e-12f

__device__ __forceinline__ float wave_reduce_sum(float v) {
#pragma unroll
    for (int m = 32; m > 0; m >>= 1) v += __shfl_xor(v, m, 64);
    return v;
}

// ---------------------------------------------------------------------------
// Kernel A: per-node attention scores. One wave per row (b*N+n), lane = c.
// ---------------------------------------------------------------------------
__global__ __launch_bounds__(256)
void k_scores(const float* __restrict__ Xr, const float* __restrict__ Xi,
              const float* __restrict__ awr, const float* __restrict__ awi,
              float* __restrict__ sRi, float* __restrict__ sIi,
              float4* __restrict__ aux) {
    const int lane = threadIdx.x & 63;
    const int row  = (blockIdx.x << 2) + (threadIdx.x >> 6);  // b*N + n
    const float xr = Xr[row * 64 + lane];
    const float xi = Xi[row * 64 + lane];
    const float wri = awr[lane], wrj = awr[64 + lane];
    const float wii = awi[lane], wij = awi[64 + lane];
    float v0 = xr * wri - xi * wii;   // sR_i partial
    float v1 = xr * wii + xi * wri;   // sI_i partial
    float v2 = xr * wrj - xi * wij;   // sR_j partial
    float v3 = xr * wij + xi * wrj;   // sI_j partial
#pragma unroll
    for (int m = 32; m > 0; m >>= 1) {
        v0 += __shfl_xor(v0, m, 64);
        v1 += __shfl_xor(v1, m, 64);
        v2 += __shfl_xor(v2, m, 64);
        v3 += __shfl_xor(v3, m, 64);
    }
    if (lane == 0) {
        sRi[row] = v0;
        sIi[row] = v1;
        aux[row].x = v2;
        aux[row].y = v3;
    }
}

// ---------------------------------------------------------------------------
// Kernel B: column softmax stats over axis i for each (b, j). One wave per
// (b, j). Writes aux.z = colmax, aux.w = 1/sum(exp(mag-colmax)).
// ---------------------------------------------------------------------------
__global__ __launch_bounds__(256)
void k_softmax(const float* __restrict__ sRi, const float* __restrict__ sIi,
               float4* __restrict__ aux,
               const float* __restrict__ abr, const float* __restrict__ abi,
               const float* __restrict__ par_, const float* __restrict__ pai_) {
    const int lane = threadIdx.x & 63;
    const int row  = (blockIdx.x << 2) + (threadIdx.x >> 6);  // b*N + j
    const int b    = row >> 10;
    const float br = abr[0], bi = abi[0], par = par_[0], pai = pai_[0];
    const float sRj = aux[row].x, sIj = aux[row].y;
    const float* pR = sRi + (b << 10);
    const float* pI = sIi + (b << 10);
    float mags[16];
    float mx = -3.4e38f;
#pragma unroll
    for (int t = 0; t < 16; ++t) {
        const int i = (t << 6) + lane;
        float sr = pR[i] + sRj + br;
        float si = pI[i] + sIj + bi;
        float pr = sr >= 0.f ? sr : par * sr;
        float pi = si >= 0.f ? si : pai * si;
        float mg = sqrtf(pr * pr + pi * pi);
        mags[t] = mg;
        mx = fmaxf(mx, mg);
    }
#pragma unroll
    for (int m = 32; m > 0; m >>= 1) mx = fmaxf(mx, __shfl_xor(mx, m, 64));
    float s = 0.f;
#pragma unroll
    for (int t = 0; t < 16; ++t) s += __expf(mags[t] - mx);
    s = wave_reduce_sum(s);
    if (lane == 0) {
        aux[row].z = mx;
        aux[row].w = 1.f / s;
    }
}

// ---------------------------------------------------------------------------
// Kernel C: the 268 MB streaming kernel. Block <-> (b, 4-row i-group).
// Phase 1: 256 threads compute ar/ai for 4 rows into 32 KB LDS. Each thread
// loads 4 coalesced aux float4 (reused across the 4 rows -> aux L2 traffic
// /4 vs prev round) and does 16 transcendental points.
// Phase 2 (one barrier): wave w streams k-slice w for all 4 rows = 32
// independent float4 global loads (4x the streaming window of the previous
// version), FMA against LDS ar/ai, butterfly-reduce 8 accumulators.
// ---------------------------------------------------------------------------
__global__ __launch_bounds__(256)
void k_rowreduce(const float* __restrict__ Lr, const float* __restrict__ Li,
                 const float* __restrict__ sRi, const float* __restrict__ sIi,
                 const float4* __restrict__ aux,
                 const float* __restrict__ abr, const float* __restrict__ abi,
                 const float* __restrict__ par_, const float* __restrict__ pai_,
                 float* __restrict__ rowR, float* __restrict__ rowI) {
    __shared__ __align__(16) float lar[4][1024];
    __shared__ __align__(16) float lai[4][1024];
    const int tid = threadIdx.x;
    const int b   = blockIdx.x >> 8;          // 256 i-groups per batch
    const int i0  = (blockIdx.x & 255) << 2;  // first of 4 rows
    const float br = abr[0], bi = abi[0], par = par_[0], pai = pai_[0];
    float sriv[4], siiv[4];
#pragma unroll
    for (int r = 0; r < 4; ++r) {
        sriv[r] = sRi[(b << 10) + i0 + r];
        siiv[r] = sIi[(b << 10) + i0 + r];
    }
    const float4* auxb = aux + (b << 10);

    // Phase 1: ar/ai for 4 rows x 1024 j. aux loaded once per j per block.
#pragma unroll
    for (int t = 0; t < 4; ++t) {
        const int j = (t << 8) + tid;
        const float4 ax = auxb[j];          // (sRj, sIj, colmax, 1/colsum)
#pragma unroll
        for (int r = 0; r < 4; ++r) {
            float sr = sriv[r] + ax.x + br;
            float si = siiv[r] + ax.y + bi;
            float pr = sr >= 0.f ? sr : par * sr;
            float pi = si >= 0.f ? si : pai * si;
            float mg = sqrtf(pr * pr + pi * pi);
            float sc = __expf(mg - ax.z) * ax.w / (mg + EPS_Q);
            lar[r][j] = sc * pr;
            lai[r][j] = sc * pi;
        }
    }
    __syncthreads();

    // Phase 2: wave w streams k-slice w for rows i0..i0+3.
    const int wave = tid >> 6, lane = tid & 63;
    float aR[4], aI[4];
#pragma unroll
    for (int r = 0; r < 4; ++r) { aR[r] = 0.f; aI[r] = 0.f; }

#pragma unroll
    for (int r = 0; r < 4; ++r) {
        const size_t base = ((size_t)((b * 4 + wave) * 1024 + (i0 + r))) * 1024;
        const float4* LR = (const float4*)(Lr + base);
        const float4* LI = (const float4*)(Li + base);
        const float4* AR = (const float4*)&lar[r][0];
        const float4* AI = (const float4*)&lai[r][0];
#pragma unroll
        for (int t = 0; t < 4; ++t) {
            const int j4 = (t << 6) + lane;
            const float4 lr = LR[j4];
            const float4 li = LI[j4];
            const float4 ar = AR[j4];
            const float4 ai = AI[j4];
            aR[r] += lr.x * ar.x - li.x * ai.x;
            aR[r] += lr.y * ar.y - li.y * ai.y;
            aR[r] += lr.z * ar.z - li.z * ai.z;
            aR[r] += lr.w * ar.w - li.w * ai.w;
            aI[r] += lr.x * ai.x + li.x * ar.x;
            aI[r] += lr.y * ai.y + li.y * ar.y;
            aI[r] += lr.z * ai.z + li.z * ar.z;
            aI[r] += lr.w * ai.w + li.w * ar.w;
        }
    }
#pragma unroll
    for (int m = 32; m > 0; m >>= 1) {
#pragma unroll
        for (int r = 0; r < 4; ++r) {
            aR[r] += __shfl_xor(aR[r], m, 64);
            aI[r] += __shfl_xor(aI[r], m, 64);
        }
    }
    if (lane == 0) {
#pragma unroll
        for (int r = 0; r < 4; ++r) {
            rowR[((b << 2) + wave) * 1024 + i0 + r] = aR[r];
            rowI[((b << 2) + wave) * 1024 + i0 + r] = aI[r];
        }
    }
}

// ---------------------------------------------------------------------------
// Kernel D: out[b,j,o] recombination; one wave handles 4 rows (register
// blocked); X rows staged in LDS.
// ---------------------------------------------------------------------------
__global__ __launch_bounds__(256)
void k_output(const float* __restrict__ Xr, const float* __restrict__ Xi,
              const float* __restrict__ wr, const float* __restrict__ wi,
              const float* __restrict__ rowR, const float* __restrict__ rowI,
              float* __restrict__ out) {
    __shared__ float lxr[16][64];
    __shared__ float lxi[16][64];
    const int tid = threadIdx.x;
    const int rb  = blockIdx.x << 4;  // 16 rows per block
    {
        const float4* s0 = (const float4*)(Xr + (size_t)rb * 64);
        const float4* s1 = (const float4*)(Xi + (size_t)rb * 64);
        ((float4*)&lxr[0][0])[tid] = s0[tid];  // 16*64 floats = 256 float4
        ((float4*)&lxi[0][0])[tid] = s1[tid];
    }
    __syncthreads();
    const int wave = tid >> 6, lane = tid & 63;
    const int r0 = wave << 2;  // 4 rows per wave
    float u[4][4], v[4][4];
#pragma unroll
    for (int r = 0; r < 4; ++r)
#pragma unroll
        for (int m = 0; m < 4; ++m) { u[r][m] = 0.f; v[r][m] = 0.f; }
    for (int c = 0; c < 64; ++c) {
        float wrv[4], wiv[4];
#pragma unroll
        for (int m = 0; m < 4; ++m) {
            wrv[m] = wr[((m << 6) + c) * 64 + lane];
            wiv[m] = wi[((m << 6) + c) * 64 + lane];
        }
#pragma unroll
        for (int r = 0; r < 4; ++r) {
            const float xr = lxr[r0 + r][c];
            const float xi = lxi[r0 + r][c];
#pragma unroll
            for (int m = 0; m < 4; ++m) {
                u[r][m] += xr * wrv[m];
                v[r][m] += xi * wiv[m];
            }
        }
    }
#pragma unroll
    for (int r = 0; r < 4; ++r) {
        const int row = rb + r0 + r;  // b*N + j
        const int b = row >> 10, j = row & 1023;
        float re = 0.f, im = 0.f;
#pragma unroll
        for (int m = 0; m < 4; ++m) {
            const float rr = rowR[(b << 12) + (m << 10) + j];
            const float ri = rowI[(b << 12) + (m << 10) + j];
            re += rr * u[r][m] - ri * v[r][m];
            im += ri * u[r][m] + rr * v[r][m];
        }
        out[(size_t)row * 64 + lane] = re;
        out[524288 + (size_t)row * 64 + lane] = im;  // imag block
    }
}

extern "C" void kernel_launch(void* const* d_in, const int* in_sizes, int n_in,
                              void* d_out, int out_size, void* d_ws, size_t ws_size,
                              hipStream_t stream) {
    const float* Xr  = (const float*)d_in[0];
    const float* Xi  = (const float*)d_in[1];
    const float* Lr  = (const float*)d_in[2];
    const float* Li  = (const float*)d_in[3];
    const float* wr  = (const float*)d_in[4];
    const float* wi  = (const float*)d_in[5];
    const float* awr = (const float*)d_in[6];
    const float* awi = (const float*)d_in[7];
    const float* abr = (const float*)d_in[8];
    const float* abi = (const float*)d_in[9];
    const float* par = (const float*)d_in[10];
    const float* pai = (const float*)d_in[11];
    float* out = (float*)d_out;

    // Workspace layout (floats): sRi[8192] | sIi[8192] | aux float4[8192]
    //                            | rowR[32768] | rowI[32768]
    float*  ws   = (float*)d_ws;
    float*  sRi  = ws;
    float*  sIi  = ws + 8192;
    float4* aux  = (float4*)(ws + 16384);
    float*  rowR = ws + 49152;
    float*  rowI = ws + 81920;

    k_scores  <<<dim3(2048), dim3(256), 0, stream>>>(Xr, Xi, awr, awi, sRi, sIi, aux);
    k_softmax <<<dim3(2048), dim3(256), 0, stream>>>(sRi, sIi, aux, abr, abi, par, pai);
    k_rowreduce<<<dim3(2048), dim3(256), 0, stream>>>(Lr, Li, sRi, sIi, aux,
                                                      abr, abi, par, pai, rowR, rowI);
    k_output  <<<dim3(512),  dim3(256), 0, stream>>>(Xr, Xi, wr, wi, rowR, rowI, out);
}

// Round 4
// 342.388 us; speedup vs baseline: 1.0074x; 1.0074x over previous
//
#include <hip/hip_runtime.h>

// Problem constants: B=8, N=1024, C=64, O=64, K+1=4
#define EPS_Q 1e-12f

__device__ __forceinline__ float wave_reduce_sum(float v) {
#pragma unroll
    for (int m = 32; m > 0; m >>= 1) v += __shfl_xor(v, m, 64);
    return v;
}

// ---------------------------------------------------------------------------
// Kernel A: per-node attention scores. One wave per row (b*N+n), lane = c.
// ---------------------------------------------------------------------------
__global__ __launch_bounds__(256)
void k_scores(const float* __restrict__ Xr, const float* __restrict__ Xi,
              const float* __restrict__ awr, const float* __restrict__ awi,
              float* __restrict__ sRi, float* __restrict__ sIi,
              float4* __restrict__ aux) {
    const int lane = threadIdx.x & 63;
    const int row  = (blockIdx.x << 2) + (threadIdx.x >> 6);  // b*N + n
    const float xr = Xr[row * 64 + lane];
    const float xi = Xi[row * 64 + lane];
    const float wri = awr[lane], wrj = awr[64 + lane];
    const float wii = awi[lane], wij = awi[64 + lane];
    float v0 = xr * wri - xi * wii;   // sR_i partial
    float v1 = xr * wii + xi * wri;   // sI_i partial
    float v2 = xr * wrj - xi * wij;   // sR_j partial
    float v3 = xr * wij + xi * wrj;   // sI_j partial
#pragma unroll
    for (int m = 32; m > 0; m >>= 1) {
        v0 += __shfl_xor(v0, m, 64);
        v1 += __shfl_xor(v1, m, 64);
        v2 += __shfl_xor(v2, m, 64);
        v3 += __shfl_xor(v3, m, 64);
    }
    if (lane == 0) {
        sRi[row] = v0;
        sIi[row] = v1;
        aux[row].x = v2;
        aux[row].y = v3;
    }
}

// ---------------------------------------------------------------------------
// Kernel B: column softmax stats over axis i for each (b, j). One wave per
// (b, j). Writes aux.z = colmax, aux.w = 1/sum(exp(mag-colmax)).
// ---------------------------------------------------------------------------
__global__ __launch_bounds__(256)
void k_softmax(const float* __restrict__ sRi, const float* __restrict__ sIi,
               float4* __restrict__ aux,
               const float* __restrict__ abr, const float* __restrict__ abi,
               const float* __restrict__ par_, const float* __restrict__ pai_) {
    const int lane = threadIdx.x & 63;
    const int row  = (blockIdx.x << 2) + (threadIdx.x >> 6);  // b*N + j
    const int b    = row >> 10;
    const float br = abr[0], bi = abi[0], par = par_[0], pai = pai_[0];
    const float sRj = aux[row].x, sIj = aux[row].y;
    const float* pR = sRi + (b << 10);
    const float* pI = sIi + (b << 10);
    float mags[16];
    float mx = -3.4e38f;
#pragma unroll
    for (int t = 0; t < 16; ++t) {
        const int i = (t << 6) + lane;
        float sr = pR[i] + sRj + br;
        float si = pI[i] + sIj + bi;
        float pr = sr >= 0.f ? sr : par * sr;
        float pi = si >= 0.f ? si : pai * si;
        float mg = sqrtf(pr * pr + pi * pi);
        mags[t] = mg;
        mx = fmaxf(mx, mg);
    }
#pragma unroll
    for (int m = 32; m > 0; m >>= 1) mx = fmaxf(mx, __shfl_xor(mx, m, 64));
    float s = 0.f;
#pragma unroll
    for (int t = 0; t < 16; ++t) s += __expf(mags[t] - mx);
    s = wave_reduce_sum(s);
    if (lane == 0) {
        aux[row].z = mx;
        aux[row].w = 1.f / s;
    }
}

// ---------------------------------------------------------------------------
// Kernel C: the 268 MB streaming kernel. R2 shape (1 row/block, 8 KB LDS,
// 8192 blocks) + register-batched streaming: all 8 float4 global loads are
// issued into named registers BEFORE any consumption (R2's VGPR_Count=28
// showed the compiler had serialized them into ~2 outstanding loads; that
// was the bandwidth cap). Consumption in load order -> early partial vmcnt.
// Two accumulator pairs break the serial FMA chain.
// ---------------------------------------------------------------------------
__global__ __launch_bounds__(256)
void k_rowreduce(const float* __restrict__ Lr, const float* __restrict__ Li,
                 const float* __restrict__ sRi, const float* __restrict__ sIi,
                 const float4* __restrict__ aux,
                 const float* __restrict__ abr, const float* __restrict__ abi,
                 const float* __restrict__ par_, const float* __restrict__ pai_,
                 float* __restrict__ rowR, float* __restrict__ rowI) {
    __shared__ __align__(16) float lar[1024];
    __shared__ __align__(16) float lai[1024];
    const int tid = threadIdx.x;
    const int row = blockIdx.x;          // b*N + i
    const int b = row >> 10;
    const int i = row & 1023;
    const float br = abr[0], bi = abi[0], par = par_[0], pai = pai_[0];
    const float sri = sRi[row], sii = sIi[row];
    const float4* auxb = aux + (b << 10);

    // Phase 1: ar/ai for all 1024 j, 4 j per thread, coalesced.
#pragma unroll
    for (int t = 0; t < 4; ++t) {
        const int j = (t << 8) + tid;
        const float4 ax = auxb[j];          // (sRj, sIj, colmax, 1/colsum)
        float sr = sri + ax.x + br;
        float si = sii + ax.y + bi;
        float pr = sr >= 0.f ? sr : par * sr;
        float pi = si >= 0.f ? si : pai * si;
        float mg = sqrtf(pr * pr + pi * pi);
        float sc = __expf(mg - ax.z) * ax.w / (mg + EPS_Q);
        lar[j] = sc * pr;
        lai[j] = sc * pi;
    }
    __syncthreads();

    // Phase 2: wave w streams k-slice w. Batch-issue ALL 8 global loads.
    const int wave = tid >> 6, lane = tid & 63;
    const size_t base = ((size_t)((b * 4 + wave) * 1024 + i)) * 1024;
    const float4* LR = (const float4*)(Lr + base);
    const float4* LI = (const float4*)(Li + base);

    const float4 g0 = LR[lane];
    const float4 g1 = LI[lane];
    const float4 g2 = LR[ 64 + lane];
    const float4 g3 = LI[ 64 + lane];
    const float4 g4 = LR[128 + lane];
    const float4 g5 = LI[128 + lane];
    const float4 g6 = LR[192 + lane];
    const float4 g7 = LI[192 + lane];

    const float4* AR = (const float4*)lar;
    const float4* AI = (const float4*)lai;
    float aR0 = 0.f, aI0 = 0.f, aR1 = 0.f, aI1 = 0.f;
    {   // t = 0: consumes g0/g1 (oldest loads -> earliest vmcnt release)
        const float4 a = AR[lane], c = AI[lane];
        aR0 += g0.x * a.x - g1.x * c.x;  aI0 += g0.x * c.x + g1.x * a.x;
        aR1 += g0.y * a.y - g1.y * c.y;  aI1 += g0.y * c.y + g1.y * a.y;
        aR0 += g0.z * a.z - g1.z * c.z;  aI0 += g0.z * c.z + g1.z * a.z;
        aR1 += g0.w * a.w - g1.w * c.w;  aI1 += g0.w * c.w + g1.w * a.w;
    }
    {   // t = 1
        const float4 a = AR[64 + lane], c = AI[64 + lane];
        aR0 += g2.x * a.x - g3.x * c.x;  aI0 += g2.x * c.x + g3.x * a.x;
        aR1 += g2.y * a.y - g3.y * c.y;  aI1 += g2.y * c.y + g3.y * a.y;
        aR0 += g2.z * a.z - g3.z * c.z;  aI0 += g2.z * c.z + g3.z * a.z;
        aR1 += g2.w * a.w - g3.w * c.w;  aI1 += g2.w * c.w + g3.w * a.w;
    }
    {   // t = 2
        const float4 a = AR[128 + lane], c = AI[128 + lane];
        aR0 += g4.x * a.x - g5.x * c.x;  aI0 += g4.x * c.x + g5.x * a.x;
        aR1 += g4.y * a.y - g5.y * c.y;  aI1 += g4.y * c.y + g5.y * a.y;
        aR0 += g4.z * a.z - g5.z * c.z;  aI0 += g4.z * c.z + g5.z * a.z;
        aR1 += g4.w * a.w - g5.w * c.w;  aI1 += g4.w * c.w + g5.w * a.w;
    }
    {   // t = 3
        const float4 a = AR[192 + lane], c = AI[192 + lane];
        aR0 += g6.x * a.x - g7.x * c.x;  aI0 += g6.x * c.x + g7.x * a.x;
        aR1 += g6.y * a.y - g7.y * c.y;  aI1 += g6.y * c.y + g7.y * a.y;
        aR0 += g6.z * a.z - g7.z * c.z;  aI0 += g6.z * c.z + g7.z * a.z;
        aR1 += g6.w * a.w - g7.w * c.w;  aI1 += g6.w * c.w + g7.w * a.w;
    }
    float aR = aR0 + aR1;
    float aI = aI0 + aI1;
#pragma unroll
    for (int m = 32; m > 0; m >>= 1) {
        aR += __shfl_xor(aR, m, 64);
        aI += __shfl_xor(aI, m, 64);
    }
    if (lane == 0) {
        rowR[((b << 2) + wave) * 1024 + i] = aR;
        rowI[((b << 2) + wave) * 1024 + i] = aI;
    }
}

// ---------------------------------------------------------------------------
// Kernel D: out[b,j,o] recombination; one wave handles 4 rows (register
// blocked); X rows staged in LDS.
// ---------------------------------------------------------------------------
__global__ __launch_bounds__(256)
void k_output(const float* __restrict__ Xr, const float* __restrict__ Xi,
              const float* __restrict__ wr, const float* __restrict__ wi,
              const float* __restrict__ rowR, const float* __restrict__ rowI,
              float* __restrict__ out) {
    __shared__ float lxr[16][64];
    __shared__ float lxi[16][64];
    const int tid = threadIdx.x;
    const int rb  = blockIdx.x << 4;  // 16 rows per block
    {
        const float4* s0 = (const float4*)(Xr + (size_t)rb * 64);
        const float4* s1 = (const float4*)(Xi + (size_t)rb * 64);
        ((float4*)&lxr[0][0])[tid] = s0[tid];  // 16*64 floats = 256 float4
        ((float4*)&lxi[0][0])[tid] = s1[tid];
    }
    __syncthreads();
    const int wave = tid >> 6, lane = tid & 63;
    const int r0 = wave << 2;  // 4 rows per wave
    float u[4][4], v[4][4];
#pragma unroll
    for (int r = 0; r < 4; ++r)
#pragma unroll
        for (int m = 0; m < 4; ++m) { u[r][m] = 0.f; v[r][m] = 0.f; }
    for (int c = 0; c < 64; ++c) {
        float wrv[4], wiv[4];
#pragma unroll
        for (int m = 0; m < 4; ++m) {
            wrv[m] = wr[((m << 6) + c) * 64 + lane];
            wiv[m] = wi[((m << 6) + c) * 64 + lane];
        }
#pragma unroll
        for (int r = 0; r < 4; ++r) {
            const float xr = lxr[r0 + r][c];
            const float xi = lxi[r0 + r][c];
#pragma unroll
            for (int m = 0; m < 4; ++m) {
                u[r][m] += xr * wrv[m];
                v[r][m] += xi * wiv[m];
            }
        }
    }
#pragma unroll
    for (int r = 0; r < 4; ++r) {
        const int row = rb + r0 + r;  // b*N + j
        const int b = row >> 10, j = row & 1023;
        float re = 0.f, im = 0.f;
#pragma unroll
        for (int m = 0; m < 4; ++m) {
            const float rr = rowR[(b << 12) + (m << 10) + j];
            const float ri = rowI[(b << 12) + (m << 10) + j];
            re += rr * u[r][m] - ri * v[r][m];
            im += ri * u[r][m] + rr * v[r][m];
        }
        out[(size_t)row * 64 + lane] = re;
        out[524288 + (size_t)row * 64 + lane] = im;  // imag block
    }
}

extern "C" void kernel_launch(void* const* d_in, const int* in_sizes, int n_in,
                              void* d_out, int out_size, void* d_ws, size_t ws_size,
                              hipStream_t stream) {
    const float* Xr  = (const float*)d_in[0];
    const float* Xi  = (const float*)d_in[1];
    const float* Lr  = (const float*)d_in[2];
    const float* Li  = (const float*)d_in[3];
    const float* wr  = (const float*)d_in[4];
    const float* wi  = (const float*)d_in[5];
    const float* awr = (const float*)d_in[6];
    const float* awi = (const float*)d_in[7];
    const float* abr = (const float*)d_in[8];
    const float* abi = (const float*)d_in[9];
    const float* par = (const float*)d_in[10];
    const float* pai = (const float*)d_in[11];
    float* out = (float*)d_out;

    // Workspace layout (floats): sRi[8192] | sIi[8192] | aux float4[8192]
    //                            | rowR[32768] | rowI[32768]
    float*  ws   = (float*)d_ws;
    float*  sRi  = ws;
    float*  sIi  = ws + 8192;
    float4* aux  = (float4*)(ws + 16384);
    float*  rowR = ws + 49152;
    float*  rowI = ws + 81920;

    k_scores  <<<dim3(2048), dim3(256), 0, stream>>>(Xr, Xi, awr, awi, sRi, sIi, aux);
    k_softmax <<<dim3(2048), dim3(256), 0, stream>>>(sRi, sIi, aux, abr, abi, par, pai);
    k_rowreduce<<<dim3(8192), dim3(256), 0, stream>>>(Lr, Li, sRi, sIi, aux,
                                                      abr, abi, par, pai, rowR, rowI);
    k_output  <<<dim3(512),  dim3(256), 0, stream>>>(Xr, Xi, wr, wi, rowR, rowI, out);
}

// Round 5
// 340.458 us; speedup vs baseline: 1.0131x; 1.0057x over previous
//
#include <hip/hip_runtime.h>

// Problem constants: B=8, N=1024, C=64, O=64, K+1=4
#define EPS_Q 1e-12f

__device__ __forceinline__ float wave_reduce_sum(float v) {
#pragma unroll
    for (int m = 32; m > 0; m >>= 1) v += __shfl_xor(v, m, 64);
    return v;
}

// ---------------------------------------------------------------------------
// Kernel A: per-node attention scores. One wave per row (b*N+n), lane = c.
// ---------------------------------------------------------------------------
__global__ __launch_bounds__(256)
void k_scores(const float* __restrict__ Xr, const float* __restrict__ Xi,
              const float* __restrict__ awr, const float* __restrict__ awi,
              float* __restrict__ sRi, float* __restrict__ sIi,
              float4* __restrict__ aux) {
    const int lane = threadIdx.x & 63;
    const int row  = (blockIdx.x << 2) + (threadIdx.x >> 6);  // b*N + n
    const float xr = Xr[row * 64 + lane];
    const float xi = Xi[row * 64 + lane];
    const float wri = awr[lane], wrj = awr[64 + lane];
    const float wii = awi[lane], wij = awi[64 + lane];
    float v0 = xr * wri - xi * wii;   // sR_i partial
    float v1 = xr * wii + xi * wri;   // sI_i partial
    float v2 = xr * wrj - xi * wij;   // sR_j partial
    float v3 = xr * wij + xi * wrj;   // sI_j partial
#pragma unroll
    for (int m = 32; m > 0; m >>= 1) {
        v0 += __shfl_xor(v0, m, 64);
        v1 += __shfl_xor(v1, m, 64);
        v2 += __shfl_xor(v2, m, 64);
        v3 += __shfl_xor(v3, m, 64);
    }
    if (lane == 0) {
        sRi[row] = v0;
        sIi[row] = v1;
        aux[row].x = v2;
        aux[row].y = v3;
    }
}

// ---------------------------------------------------------------------------
// Kernel B: column softmax stats over axis i for each (b, j). One wave per
// (b, j). Writes aux.z = colmax, aux.w = 1/sum(exp(mag-colmax)).
// ---------------------------------------------------------------------------
__global__ __launch_bounds__(256)
void k_softmax(const float* __restrict__ sRi, const float* __restrict__ sIi,
               float4* __restrict__ aux,
               const float* __restrict__ abr, const float* __restrict__ abi,
               const float* __restrict__ par_, const float* __restrict__ pai_) {
    const int lane = threadIdx.x & 63;
    const int row  = (blockIdx.x << 2) + (threadIdx.x >> 6);  // b*N + j
    const int b    = row >> 10;
    const float br = abr[0], bi = abi[0], par = par_[0], pai = pai_[0];
    const float sRj = aux[row].x, sIj = aux[row].y;
    const float* pR = sRi + (b << 10);
    const float* pI = sIi + (b << 10);
    float mags[16];
    float mx = -3.4e38f;
#pragma unroll
    for (int t = 0; t < 16; ++t) {
        const int i = (t << 6) + lane;
        float sr = pR[i] + sRj + br;
        float si = pI[i] + sIj + bi;
        float pr = sr >= 0.f ? sr : par * sr;
        float pi = si >= 0.f ? si : pai * si;
        float mg = sqrtf(pr * pr + pi * pi);
        mags[t] = mg;
        mx = fmaxf(mx, mg);
    }
#pragma unroll
    for (int m = 32; m > 0; m >>= 1) mx = fmaxf(mx, __shfl_xor(mx, m, 64));
    float s = 0.f;
#pragma unroll
    for (int t = 0; t < 16; ++t) s += __expf(mags[t] - mx);
    s = wave_reduce_sum(s);
    if (lane == 0) {
        aux[row].z = mx;
        aux[row].w = 1.f / s;
    }
}

// ---------------------------------------------------------------------------
// Kernel C: the 268 MB streaming kernel. R2 shape (1 row/block, 8192 blocks)
// but the L streams now go through async global->LDS DMA
// (__builtin_amdgcn_global_load_lds): NO VGPR destination, so the register-
// pressure scheduler (which pinned R2/R4 at ~2 outstanding loads, VGPR=28)
// cannot serialize them. Each wave issues 8 x 1KB DMAs back-to-back into a
// private 8 KB LDS stage, then drains with partial vmcnt waits (AITER idiom)
// while FMA-ing earlier chunks against lar/lai.
// ---------------------------------------------------------------------------
__global__ __launch_bounds__(256)
void k_rowreduce(const float* __restrict__ Lr, const float* __restrict__ Li,
                 const float* __restrict__ sRi, const float* __restrict__ sIi,
                 const float4* __restrict__ aux,
                 const float* __restrict__ abr, const float* __restrict__ abi,
                 const float* __restrict__ par_, const float* __restrict__ pai_,
                 float* __restrict__ rowR, float* __restrict__ rowI) {
    __shared__ __align__(16) float lar[1024];
    __shared__ __align__(16) float lai[1024];
    __shared__ __align__(16) float stage[4][2048];  // per-wave: Lr[1024] | Li[1024]
    const int tid = threadIdx.x;
    const int row = blockIdx.x;          // b*N + i
    const int b = row >> 10;
    const int i = row & 1023;
    const float br = abr[0], bi = abi[0], par = par_[0], pai = pai_[0];
    const float sri = sRi[row], sii = sIi[row];
    const float4* auxb = aux + (b << 10);

    // Phase 1: ar/ai for all 1024 j, 4 j per thread, coalesced.
#pragma unroll
    for (int t = 0; t < 4; ++t) {
        const int j = (t << 8) + tid;
        const float4 ax = auxb[j];          // (sRj, sIj, colmax, 1/colsum)
        float sr = sri + ax.x + br;
        float si = sii + ax.y + bi;
        float pr = sr >= 0.f ? sr : par * sr;
        float pi = si >= 0.f ? si : pai * si;
        float mg = sqrtf(pr * pr + pi * pi);
        float sc = __expf(mg - ax.z) * ax.w / (mg + EPS_Q);
        lar[j] = sc * pr;
        lai[j] = sc * pi;
    }
    __syncthreads();

    // Phase 2: wave w streams k-slice w via async global->LDS DMA.
    const int wave = tid >> 6, lane = tid & 63;
    const size_t base = ((size_t)((b * 4 + wave) * 1024 + i)) * 1024;
    const float* LRp = Lr + base;
    const float* LIp = Li + base;
    float* st = &stage[wave][0];

    // Issue all 8 DMAs (each: 64 lanes x 16 B = 1 KB, LDS dest = uniform
    // base + lane*16, matching the contiguous consumption layout below).
#pragma unroll
    for (int t = 0; t < 4; ++t) {
        __builtin_amdgcn_global_load_lds(
            (const __attribute__((address_space(1))) void*)(LRp + ((t << 6) + lane) * 4),
            (__attribute__((address_space(3))) void*)(st + (t << 8)), 16, 0, 0);
        __builtin_amdgcn_global_load_lds(
            (const __attribute__((address_space(1))) void*)(LIp + ((t << 6) + lane) * 4),
            (__attribute__((address_space(3))) void*)(st + 1024 + (t << 8)), 16, 0, 0);
    }

    const float4* SR = (const float4*)st;            // Lr chunks [256]
    const float4* SI = (const float4*)(st + 1024);   // Li chunks [256]
    const float4* AR = (const float4*)lar;
    const float4* AI = (const float4*)lai;
    float aR0 = 0.f, aI0 = 0.f, aR1 = 0.f, aI1 = 0.f;
    // Partial drains: vmcnt(6) -> t0 pair arrived, vmcnt(4) -> t1, ...
    // s_waitcnt imm: vmcnt[3:0] | expcnt=7 [6:4] | lgkmcnt=15 [11:8]
#pragma unroll
    for (int t = 0; t < 4; ++t) {
        switch (t) {
            case 0: __builtin_amdgcn_s_waitcnt(0x0F76); break;
            case 1: __builtin_amdgcn_s_waitcnt(0x0F74); break;
            case 2: __builtin_amdgcn_s_waitcnt(0x0F72); break;
            default: __builtin_amdgcn_s_waitcnt(0x0F70); break;
        }
        const int idx = (t << 6) + lane;
        const float4 g = SR[idx];
        const float4 h = SI[idx];
        const float4 a = AR[idx];
        const float4 c = AI[idx];
        aR0 += g.x * a.x - h.x * c.x;  aI0 += g.x * c.x + h.x * a.x;
        aR1 += g.y * a.y - h.y * c.y;  aI1 += g.y * c.y + h.y * a.y;
        aR0 += g.z * a.z - h.z * c.z;  aI0 += g.z * c.z + h.z * a.z;
        aR1 += g.w * a.w - h.w * c.w;  aI1 += g.w * c.w + h.w * a.w;
    }
    float aR = aR0 + aR1;
    float aI = aI0 + aI1;
#pragma unroll
    for (int m = 32; m > 0; m >>= 1) {
        aR += __shfl_xor(aR, m, 64);
        aI += __shfl_xor(aI, m, 64);
    }
    if (lane == 0) {
        rowR[((b << 2) + wave) * 1024 + i] = aR;
        rowI[((b << 2) + wave) * 1024 + i] = aI;
    }
}

// ---------------------------------------------------------------------------
// Kernel D: out[b,j,o] recombination; one wave handles 4 rows (register
// blocked); X rows staged in LDS.
// ---------------------------------------------------------------------------
__global__ __launch_bounds__(256)
void k_output(const float* __restrict__ Xr, const float* __restrict__ Xi,
              const float* __restrict__ wr, const float* __restrict__ wi,
              const float* __restrict__ rowR, const float* __restrict__ rowI,
              float* __restrict__ out) {
    __shared__ float lxr[16][64];
    __shared__ float lxi[16][64];
    const int tid = threadIdx.x;
    const int rb  = blockIdx.x << 4;  // 16 rows per block
    {
        const float4* s0 = (const float4*)(Xr + (size_t)rb * 64);
        const float4* s1 = (const float4*)(Xi + (size_t)rb * 64);
        ((float4*)&lxr[0][0])[tid] = s0[tid];  // 16*64 floats = 256 float4
        ((float4*)&lxi[0][0])[tid] = s1[tid];
    }
    __syncthreads();
    const int wave = tid >> 6, lane = tid & 63;
    const int r0 = wave << 2;  // 4 rows per wave
    float u[4][4], v[4][4];
#pragma unroll
    for (int r = 0; r < 4; ++r)
#pragma unroll
        for (int m = 0; m < 4; ++m) { u[r][m] = 0.f; v[r][m] = 0.f; }
    for (int c = 0; c < 64; ++c) {
        float wrv[4], wiv[4];
#pragma unroll
        for (int m = 0; m < 4; ++m) {
            wrv[m] = wr[((m << 6) + c) * 64 + lane];
            wiv[m] = wi[((m << 6) + c) * 64 + lane];
        }
#pragma unroll
        for (int r = 0; r < 4; ++r) {
            const float xr = lxr[r0 + r][c];
            const float xi = lxi[r0 + r][c];
#pragma unroll
            for (int m = 0; m < 4; ++m) {
                u[r][m] += xr * wrv[m];
                v[r][m] += xi * wiv[m];
            }
        }
    }
#pragma unroll
    for (int r = 0; r < 4; ++r) {
        const int row = rb + r0 + r;  // b*N + j
        const int b = row >> 10, j = row & 1023;
        float re = 0.f, im = 0.f;
#pragma unroll
        for (int m = 0; m < 4; ++m) {
            const float rr = rowR[(b << 12) + (m << 10) + j];
            const float ri = rowI[(b << 12) + (m << 10) + j];
            re += rr * u[r][m] - ri * v[r][m];
            im += ri * u[r][m] + rr * v[r][m];
        }
        out[(size_t)row * 64 + lane] = re;
        out[524288 + (size_t)row * 64 + lane] = im;  // imag block
    }
}

extern "C" void kernel_launch(void* const* d_in, const int* in_sizes, int n_in,
                              void* d_out, int out_size, void* d_ws, size_t ws_size,
                              hipStream_t stream) {
    const float* Xr  = (const float*)d_in[0];
    const float* Xi  = (const float*)d_in[1];
    const float* Lr  = (const float*)d_in[2];
    const float* Li  = (const float*)d_in[3];
    const float* wr  = (const float*)d_in[4];
    const float* wi  = (const float*)d_in[5];
    const float* awr = (const float*)d_in[6];
    const float* awi = (const float*)d_in[7];
    const float* abr = (const float*)d_in[8];
    const float* abi = (const float*)d_in[9];
    const float* par = (const float*)d_in[10];
    const float* pai = (const float*)d_in[11];
    float* out = (float*)d_out;

    // Workspace layout (floats): sRi[8192] | sIi[8192] | aux float4[8192]
    //                            | rowR[32768] | rowI[32768]
    float*  ws   = (float*)d_ws;
    float*  sRi  = ws;
    float*  sIi  = ws + 8192;
    float4* aux  = (float4*)(ws + 16384);
    float*  rowR = ws + 49152;
    float*  rowI = ws + 81920;

    k_scores  <<<dim3(2048), dim3(256), 0, stream>>>(Xr, Xi, awr, awi, sRi, sIi, aux);
    k_softmax <<<dim3(2048), dim3(256), 0, stream>>>(sRi, sIi, aux, abr, abi, par, pai);
    k_rowreduce<<<dim3(8192), dim3(256), 0, stream>>>(Lr, Li, sRi, sIi, aux,
                                                      abr, abi, par, pai, rowR, rowI);
    k_output  <<<dim3(512),  dim3(256), 0, stream>>>(Xr, Xi, wr, wi, rowR, rowI, out);
}

// Round 7
// 324.423 us; speedup vs baseline: 1.0632x; 1.0494x over previous
//
#include <hip/hip_runtime.h>

// Problem constants: B=8, N=1024, C=64, O=64, K+1=4
#define EPS_Q 1e-12f

// Native clang vector for __builtin_nontemporal_load (HIP_vector_type is
// rejected by the builtin's type checker).
typedef float nfloat4 __attribute__((ext_vector_type(4)));

__device__ __forceinline__ float wave_reduce_sum(float v) {
#pragma unroll
    for (int m = 32; m > 0; m >>= 1) v += __shfl_xor(v, m, 64);
    return v;
}

// ---------------------------------------------------------------------------
// Kernel A: per-node attention scores. One wave per row (b*N+n), lane = c.
// ---------------------------------------------------------------------------
__global__ __launch_bounds__(256)
void k_scores(const float* __restrict__ Xr, const float* __restrict__ Xi,
              const float* __restrict__ awr, const float* __restrict__ awi,
              float* __restrict__ sRi, float* __restrict__ sIi,
              float4* __restrict__ aux) {
    const int lane = threadIdx.x & 63;
    const int row  = (blockIdx.x << 2) + (threadIdx.x >> 6);  // b*N + n
    const float xr = Xr[row * 64 + lane];
    const float xi = Xi[row * 64 + lane];
    const float wri = awr[lane], wrj = awr[64 + lane];
    const float wii = awi[lane], wij = awi[64 + lane];
    float v0 = xr * wri - xi * wii;   // sR_i partial
    float v1 = xr * wii + xi * wri;   // sI_i partial
    float v2 = xr * wrj - xi * wij;   // sR_j partial
    float v3 = xr * wij + xi * wrj;   // sI_j partial
#pragma unroll
    for (int m = 32; m > 0; m >>= 1) {
        v0 += __shfl_xor(v0, m, 64);
        v1 += __shfl_xor(v1, m, 64);
        v2 += __shfl_xor(v2, m, 64);
        v3 += __shfl_xor(v3, m, 64);
    }
    if (lane == 0) {
        sRi[row] = v0;
        sIi[row] = v1;
        aux[row].x = v2;
        aux[row].y = v3;
    }
}

// ---------------------------------------------------------------------------
// Kernel B: column softmax stats over axis i for each (b, j). One wave per
// (b, j). Writes aux.z = colmax, aux.w = 1/sum(exp(mag-colmax)).
// ---------------------------------------------------------------------------
__global__ __launch_bounds__(256)
void k_softmax(const float* __restrict__ sRi, const float* __restrict__ sIi,
               float4* __restrict__ aux,
               const float* __restrict__ abr, const float* __restrict__ abi,
               const float* __restrict__ par_, const float* __restrict__ pai_) {
    const int lane = threadIdx.x & 63;
    const int row  = (blockIdx.x << 2) + (threadIdx.x >> 6);  // b*N + j
    const int b    = row >> 10;
    const float br = abr[0], bi = abi[0], par = par_[0], pai = pai_[0];
    const float sRj = aux[row].x, sIj = aux[row].y;
    const float* pR = sRi + (b << 10);
    const float* pI = sIi + (b << 10);
    float mags[16];
    float mx = -3.4e38f;
#pragma unroll
    for (int t = 0; t < 16; ++t) {
        const int i = (t << 6) + lane;
        float sr = pR[i] + sRj + br;
        float si = pI[i] + sIj + bi;
        float pr = sr >= 0.f ? sr : par * sr;
        float pi = si >= 0.f ? si : pai * si;
        float mg = sqrtf(pr * pr + pi * pi);
        mags[t] = mg;
        mx = fmaxf(mx, mg);
    }
#pragma unroll
    for (int m = 32; m > 0; m >>= 1) mx = fmaxf(mx, __shfl_xor(mx, m, 64));
    float s = 0.f;
#pragma unroll
    for (int t = 0; t < 16; ++t) s += __expf(mags[t] - mx);
    s = wave_reduce_sum(s);
    if (lane == 0) {
        aux[row].z = mx;
        aux[row].w = 1.f / s;
    }
}

// ---------------------------------------------------------------------------
// Kernel C: the 268 MB streaming kernel. R2 shape (best: 1 row/block, 8 KB
// LDS, 8192 blocks, occupancy ~75%) with ONE change: the 8 L-stream loads are
// NONTEMPORAL (nt cache policy -> bypass L1 allocation/miss tracking). All
// four structural variants (R1/R2/R3/R5) pinned at ~2.8 TB/s demand BW
// regardless of occupancy or in-flight depth -> per-CU L1 MSHR ceiling is the
// suspected wall. L has zero reuse, so L1 caching of it is pure loss anyway.
// ---------------------------------------------------------------------------
__global__ __launch_bounds__(256)
void k_rowreduce(const float* __restrict__ Lr, const float* __restrict__ Li,
                 const float* __restrict__ sRi, const float* __restrict__ sIi,
                 const float4* __restrict__ aux,
                 const float* __restrict__ abr, const float* __restrict__ abi,
                 const float* __restrict__ par_, const float* __restrict__ pai_,
                 float* __restrict__ rowR, float* __restrict__ rowI) {
    __shared__ __align__(16) float lar[1024];
    __shared__ __align__(16) float lai[1024];
    const int tid = threadIdx.x;
    const int row = blockIdx.x;          // b*N + i
    const int b = row >> 10;
    const int i = row & 1023;
    const float br = abr[0], bi = abi[0], par = par_[0], pai = pai_[0];
    const float sri = sRi[row], sii = sIi[row];
    const float4* auxb = aux + (b << 10);

    // Phase 1: ar/ai for all 1024 j, 4 j per thread, coalesced (cached loads:
    // aux IS reused across the 1024 blocks of this batch).
#pragma unroll
    for (int t = 0; t < 4; ++t) {
        const int j = (t << 8) + tid;
        const float4 ax = auxb[j];          // (sRj, sIj, colmax, 1/colsum)
        float sr = sri + ax.x + br;
        float si = sii + ax.y + bi;
        float pr = sr >= 0.f ? sr : par * sr;
        float pi = si >= 0.f ? si : pai * si;
        float mg = sqrtf(pr * pr + pi * pi);
        float sc = __expf(mg - ax.z) * ax.w / (mg + EPS_Q);
        lar[j] = sc * pr;
        lai[j] = sc * pi;
    }
    __syncthreads();

    // Phase 2: wave w streams k-slice w with NONTEMPORAL float4 loads.
    const int wave = tid >> 6, lane = tid & 63;
    const size_t base = ((size_t)((b * 4 + wave) * 1024 + i)) * 1024;
    const nfloat4* LR = (const nfloat4*)(Lr + base);
    const nfloat4* LI = (const nfloat4*)(Li + base);
    const float4* AR = (const float4*)lar;
    const float4* AI = (const float4*)lai;
    float aR0 = 0.f, aI0 = 0.f, aR1 = 0.f, aI1 = 0.f;
#pragma unroll
    for (int t = 0; t < 4; ++t) {
        const int j4 = (t << 6) + lane;
        const nfloat4 lr = __builtin_nontemporal_load(&LR[j4]);
        const nfloat4 li = __builtin_nontemporal_load(&LI[j4]);
        const float4 a = AR[j4];
        const float4 c = AI[j4];
        aR0 += lr.x * a.x - li.x * c.x;  aI0 += lr.x * c.x + li.x * a.x;
        aR1 += lr.y * a.y - li.y * c.y;  aI1 += lr.y * c.y + li.y * a.y;
        aR0 += lr.z * a.z - li.z * c.z;  aI0 += lr.z * c.z + li.z * a.z;
        aR1 += lr.w * a.w - li.w * c.w;  aI1 += lr.w * c.w + li.w * a.w;
    }
    float aR = aR0 + aR1;
    float aI = aI0 + aI1;
#pragma unroll
    for (int m = 32; m > 0; m >>= 1) {
        aR += __shfl_xor(aR, m, 64);
        aI += __shfl_xor(aI, m, 64);
    }
    if (lane == 0) {
        rowR[((b << 2) + wave) * 1024 + i] = aR;
        rowI[((b << 2) + wave) * 1024 + i] = aI;
    }
}

// ---------------------------------------------------------------------------
// Kernel D: out[b,j,o] recombination; one wave handles 4 rows (register
// blocked); X rows staged in LDS.
// ---------------------------------------------------------------------------
__global__ __launch_bounds__(256)
void k_output(const float* __restrict__ Xr, const float* __restrict__ Xi,
              const float* __restrict__ wr, const float* __restrict__ wi,
              const float* __restrict__ rowR, const float* __restrict__ rowI,
              float* __restrict__ out) {
    __shared__ float lxr[16][64];
    __shared__ float lxi[16][64];
    const int tid = threadIdx.x;
    const int rb  = blockIdx.x << 4;  // 16 rows per block
    {
        const float4* s0 = (const float4*)(Xr + (size_t)rb * 64);
        const float4* s1 = (const float4*)(Xi + (size_t)rb * 64);
        ((float4*)&lxr[0][0])[tid] = s0[tid];  // 16*64 floats = 256 float4
        ((float4*)&lxi[0][0])[tid] = s1[tid];
    }
    __syncthreads();
    const int wave = tid >> 6, lane = tid & 63;
    const int r0 = wave << 2;  // 4 rows per wave
    float u[4][4], v[4][4];
#pragma unroll
    for (int r = 0; r < 4; ++r)
#pragma unroll
        for (int m = 0; m < 4; ++m) { u[r][m] = 0.f; v[r][m] = 0.f; }
    for (int c = 0; c < 64; ++c) {
        float wrv[4], wiv[4];
#pragma unroll
        for (int m = 0; m < 4; ++m) {
            wrv[m] = wr[((m << 6) + c) * 64 + lane];
            wiv[m] = wi[((m << 6) + c) * 64 + lane];
        }
#pragma unroll
        for (int r = 0; r < 4; ++r) {
            const float xr = lxr[r0 + r][c];
            const float xi = lxi[r0 + r][c];
#pragma unroll
            for (int m = 0; m < 4; ++m) {
                u[r][m] += xr * wrv[m];
                v[r][m] += xi * wiv[m];
            }
        }
    }
#pragma unroll
    for (int r = 0; r < 4; ++r) {
        const int row = rb + r0 + r;  // b*N + j
        const int b = row >> 10, j = row & 1023;
        float re = 0.f, im = 0.f;
#pragma unroll
        for (int m = 0; m < 4; ++m) {
            const float rr = rowR[(b << 12) + (m << 10) + j];
            const float ri = rowI[(b << 12) + (m << 10) + j];
            re += rr * u[r][m] - ri * v[r][m];
            im += ri * u[r][m] + rr * v[r][m];
        }
        out[(size_t)row * 64 + lane] = re;
        out[524288 + (size_t)row * 64 + lane] = im;  // imag block
    }
}

extern "C" void kernel_launch(void* const* d_in, const int* in_sizes, int n_in,
                              void* d_out, int out_size, void* d_ws, size_t ws_size,
                              hipStream_t stream) {
    const float* Xr  = (const float*)d_in[0];
    const float* Xi  = (const float*)d_in[1];
    const float* Lr  = (const float*)d_in[2];
    const float* Li  = (const float*)d_in[3];
    const float* wr  = (const float*)d_in[4];
    const float* wi  = (const float*)d_in[5];
    const float* awr = (const float*)d_in[6];
    const float* awi = (const float*)d_in[7];
    const float* abr = (const float*)d_in[8];
    const float* abi = (const float*)d_in[9];
    const float* par = (const float*)d_in[10];
    const float* pai = (const float*)d_in[11];
    float* out = (float*)d_out;

    // Workspace layout (floats): sRi[8192] | sIi[8192] | aux float4[8192]
    //                            | rowR[32768] | rowI[32768]
    float*  ws   = (float*)d_ws;
    float*  sRi  = ws;
    float*  sIi  = ws + 8192;
    float4* aux  = (float4*)(ws + 16384);
    float*  rowR = ws + 49152;
    float*  rowI = ws + 81920;

    k_scores  <<<dim3(2048), dim3(256), 0, stream>>>(Xr, Xi, awr, awi, sRi, sIi, aux);
    k_softmax <<<dim3(2048), dim3(256), 0, stream>>>(sRi, sIi, aux, abr, abi, par, pai);
    k_rowreduce<<<dim3(8192), dim3(256), 0, stream>>>(Lr, Li, sRi, sIi, aux,
                                                      abr, abi, par, pai, rowR, rowI);
    k_output  <<<dim3(512),  dim3(256), 0, stream>>>(Xr, Xi, wr, wi, rowR, rowI, out);
}

// Round 8
// 320.050 us; speedup vs baseline: 1.0777x; 1.0137x over previous
//
#include <hip/hip_runtime.h>

// Problem constants: B=8, N=1024, C=64, O=64, K+1=4
#define EPS_Q 1e-12f

// Native clang vector for __builtin_nontemporal_load (HIP_vector_type is
// rejected by the builtin's type checker).
typedef float nfloat4 __attribute__((ext_vector_type(4)));

__device__ __forceinline__ float wave_reduce_sum(float v) {
#pragma unroll
    for (int m = 32; m > 0; m >>= 1) v += __shfl_xor(v, m, 64);
    return v;
}

// ---------------------------------------------------------------------------
// Kernel A: per-node attention scores. One wave per row (b*N+n), lane = c.
// ---------------------------------------------------------------------------
__global__ __launch_bounds__(256)
void k_scores(const float* __restrict__ Xr, const float* __restrict__ Xi,
              const float* __restrict__ awr, const float* __restrict__ awi,
              float* __restrict__ sRi, float* __restrict__ sIi,
              float4* __restrict__ aux) {
    const int lane = threadIdx.x & 63;
    const int row  = (blockIdx.x << 2) + (threadIdx.x >> 6);  // b*N + n
    const float xr = Xr[row * 64 + lane];
    const float xi = Xi[row * 64 + lane];
    const float wri = awr[lane], wrj = awr[64 + lane];
    const float wii = awi[lane], wij = awi[64 + lane];
    float v0 = xr * wri - xi * wii;   // sR_i partial
    float v1 = xr * wii + xi * wri;   // sI_i partial
    float v2 = xr * wrj - xi * wij;   // sR_j partial
    float v3 = xr * wij + xi * wrj;   // sI_j partial
#pragma unroll
    for (int m = 32; m > 0; m >>= 1) {
        v0 += __shfl_xor(v0, m, 64);
        v1 += __shfl_xor(v1, m, 64);
        v2 += __shfl_xor(v2, m, 64);
        v3 += __shfl_xor(v3, m, 64);
    }
    if (lane == 0) {
        sRi[row] = v0;
        sIi[row] = v1;
        aux[row].x = v2;
        aux[row].y = v3;
    }
}

// ---------------------------------------------------------------------------
// Kernel B: column softmax stats over axis i for each (b, j). One wave per
// (b, j). Writes aux.z = colmax, aux.w = 1/sum(exp(mag-colmax)).
// ---------------------------------------------------------------------------
__global__ __launch_bounds__(256)
void k_softmax(const float* __restrict__ sRi, const float* __restrict__ sIi,
               float4* __restrict__ aux,
               const float* __restrict__ abr, const float* __restrict__ abi,
               const float* __restrict__ par_, const float* __restrict__ pai_) {
    const int lane = threadIdx.x & 63;
    const int row  = (blockIdx.x << 2) + (threadIdx.x >> 6);  // b*N + j
    const int b    = row >> 10;
    const float br = abr[0], bi = abi[0], par = par_[0], pai = pai_[0];
    const float sRj = aux[row].x, sIj = aux[row].y;
    const float* pR = sRi + (b << 10);
    const float* pI = sIi + (b << 10);
    float mags[16];
    float mx = -3.4e38f;
#pragma unroll
    for (int t = 0; t < 16; ++t) {
        const int i = (t << 6) + lane;
        float sr = pR[i] + sRj + br;
        float si = pI[i] + sIj + bi;
        float pr = sr >= 0.f ? sr : par * sr;
        float pi = si >= 0.f ? si : pai * si;
        float mg = sqrtf(pr * pr + pi * pi);
        mags[t] = mg;
        mx = fmaxf(mx, mg);
    }
#pragma unroll
    for (int m = 32; m > 0; m >>= 1) mx = fmaxf(mx, __shfl_xor(mx, m, 64));
    float s = 0.f;
#pragma unroll
    for (int t = 0; t < 16; ++t) s += __expf(mags[t] - mx);
    s = wave_reduce_sum(s);
    if (lane == 0) {
        aux[row].z = mx;
        aux[row].w = 1.f / s;
    }
}

// ---------------------------------------------------------------------------
// Kernel C: the 268 MB streaming kernel. R7 (nt loads, L1 bypass) + 2 rows
// per block: phase-1 aux is loaded once and reused for both rows, and each
// wave streams 16 KB per barrier instead of 8 KB -> streaming duty cycle ~2x
// (R7's Little's-law analysis: the wall is waves spending only ~15% of their
// life with loads in flight). LDS 16 KB keeps 8-blocks/CU occupancy cap,
// grid 4096 keeps 16 blocks/CU available (R3's 4-row variant died on
// occupancy: 32 KB LDS + VGPR 108 + grid 2048).
// ---------------------------------------------------------------------------
__global__ __launch_bounds__(256)
void k_rowreduce(const float* __restrict__ Lr, const float* __restrict__ Li,
                 const float* __restrict__ sRi, const float* __restrict__ sIi,
                 const float4* __restrict__ aux,
                 const float* __restrict__ abr, const float* __restrict__ abi,
                 const float* __restrict__ par_, const float* __restrict__ pai_,
                 float* __restrict__ rowR, float* __restrict__ rowI) {
    __shared__ __align__(16) float lar[2][1024];
    __shared__ __align__(16) float lai[2][1024];
    const int tid = threadIdx.x;
    const int b   = blockIdx.x >> 9;          // 512 2-row groups per batch
    const int i0  = (blockIdx.x & 511) << 1;  // first of 2 rows
    const float br = abr[0], bi = abi[0], par = par_[0], pai = pai_[0];
    const float sri0 = sRi[(b << 10) + i0],     sii0 = sIi[(b << 10) + i0];
    const float sri1 = sRi[(b << 10) + i0 + 1], sii1 = sIi[(b << 10) + i0 + 1];
    const float4* auxb = aux + (b << 10);

    // Phase 1: ar/ai for 2 rows x 1024 j; aux loaded ONCE per j per block.
#pragma unroll
    for (int t = 0; t < 4; ++t) {
        const int j = (t << 8) + tid;
        const float4 ax = auxb[j];          // (sRj, sIj, colmax, 1/colsum)
        {
            float sr = sri0 + ax.x + br;
            float si = sii0 + ax.y + bi;
            float pr = sr >= 0.f ? sr : par * sr;
            float pi = si >= 0.f ? si : pai * si;
            float mg = sqrtf(pr * pr + pi * pi);
            float sc = __expf(mg - ax.z) * ax.w / (mg + EPS_Q);
            lar[0][j] = sc * pr;
            lai[0][j] = sc * pi;
        }
        {
            float sr = sri1 + ax.x + br;
            float si = sii1 + ax.y + bi;
            float pr = sr >= 0.f ? sr : par * sr;
            float pi = si >= 0.f ? si : pai * si;
            float mg = sqrtf(pr * pr + pi * pi);
            float sc = __expf(mg - ax.z) * ax.w / (mg + EPS_Q);
            lar[1][j] = sc * pr;
            lai[1][j] = sc * pi;
        }
    }
    __syncthreads();

    // Phase 2: wave w streams k-slice w for both rows with NT float4 loads.
    const int wave = tid >> 6, lane = tid & 63;
#pragma unroll
    for (int r = 0; r < 2; ++r) {
        const size_t base = ((size_t)((b * 4 + wave) * 1024 + (i0 + r))) * 1024;
        const nfloat4* LR = (const nfloat4*)(Lr + base);
        const nfloat4* LI = (const nfloat4*)(Li + base);
        const float4* AR = (const float4*)&lar[r][0];
        const float4* AI = (const float4*)&lai[r][0];
        float aR0 = 0.f, aI0 = 0.f, aR1 = 0.f, aI1 = 0.f;
#pragma unroll
        for (int t = 0; t < 4; ++t) {
            const int j4 = (t << 6) + lane;
            const nfloat4 lr = __builtin_nontemporal_load(&LR[j4]);
            const nfloat4 li = __builtin_nontemporal_load(&LI[j4]);
            const float4 a = AR[j4];
            const float4 c = AI[j4];
            aR0 += lr.x * a.x - li.x * c.x;  aI0 += lr.x * c.x + li.x * a.x;
            aR1 += lr.y * a.y - li.y * c.y;  aI1 += lr.y * c.y + li.y * a.y;
            aR0 += lr.z * a.z - li.z * c.z;  aI0 += lr.z * c.z + li.z * a.z;
            aR1 += lr.w * a.w - li.w * c.w;  aI1 += lr.w * c.w + li.w * a.w;
        }
        float aR = aR0 + aR1;
        float aI = aI0 + aI1;
#pragma unroll
        for (int m = 32; m > 0; m >>= 1) {
            aR += __shfl_xor(aR, m, 64);
            aI += __shfl_xor(aI, m, 64);
        }
        if (lane == 0) {
            rowR[((b << 2) + wave) * 1024 + i0 + r] = aR;
            rowI[((b << 2) + wave) * 1024 + i0 + r] = aI;
        }
    }
}

// ---------------------------------------------------------------------------
// Kernel D: out[b,j,o] recombination; one wave handles 4 rows (register
// blocked); X rows staged in LDS.
// ---------------------------------------------------------------------------
__global__ __launch_bounds__(256)
void k_output(const float* __restrict__ Xr, const float* __restrict__ Xi,
              const float* __restrict__ wr, const float* __restrict__ wi,
              const float* __restrict__ rowR, const float* __restrict__ rowI,
              float* __restrict__ out) {
    __shared__ float lxr[16][64];
    __shared__ float lxi[16][64];
    const int tid = threadIdx.x;
    const int rb  = blockIdx.x << 4;  // 16 rows per block
    {
        const float4* s0 = (const float4*)(Xr + (size_t)rb * 64);
        const float4* s1 = (const float4*)(Xi + (size_t)rb * 64);
        ((float4*)&lxr[0][0])[tid] = s0[tid];  // 16*64 floats = 256 float4
        ((float4*)&lxi[0][0])[tid] = s1[tid];
    }
    __syncthreads();
    const int wave = tid >> 6, lane = tid & 63;
    const int r0 = wave << 2;  // 4 rows per wave
    float u[4][4], v[4][4];
#pragma unroll
    for (int r = 0; r < 4; ++r)
#pragma unroll
        for (int m = 0; m < 4; ++m) { u[r][m] = 0.f; v[r][m] = 0.f; }
    for (int c = 0; c < 64; ++c) {
        float wrv[4], wiv[4];
#pragma unroll
        for (int m = 0; m < 4; ++m) {
            wrv[m] = wr[((m << 6) + c) * 64 + lane];
            wiv[m] = wi[((m << 6) + c) * 64 + lane];
        }
#pragma unroll
        for (int r = 0; r < 4; ++r) {
            const float xr = lxr[r0 + r][c];
            const float xi = lxi[r0 + r][c];
#pragma unroll
            for (int m = 0; m < 4; ++m) {
                u[r][m] += xr * wrv[m];
                v[r][m] += xi * wiv[m];
            }
        }
    }
#pragma unroll
    for (int r = 0; r < 4; ++r) {
        const int row = rb + r0 + r;  // b*N + j
        const int b = row >> 10, j = row & 1023;
        float re = 0.f, im = 0.f;
#pragma unroll
        for (int m = 0; m < 4; ++m) {
            const float rr = rowR[(b << 12) + (m << 10) + j];
            const float ri = rowI[(b << 12) + (m << 10) + j];
            re += rr * u[r][m] - ri * v[r][m];
            im += ri * u[r][m] + rr * v[r][m];
        }
        out[(size_t)row * 64 + lane] = re;
        out[524288 + (size_t)row * 64 + lane] = im;  // imag block
    }
}

extern "C" void kernel_launch(void* const* d_in, const int* in_sizes, int n_in,
                              void* d_out, int out_size, void* d_ws, size_t ws_size,
                              hipStream_t stream) {
    const float* Xr  = (const float*)d_in[0];
    const float* Xi  = (const float*)d_in[1];
    const float* Lr  = (const float*)d_in[2];
    const float* Li  = (const float*)d_in[3];
    const float* wr  = (const float*)d_in[4];
    const float* wi  = (const float*)d_in[5];
    const float* awr = (const float*)d_in[6];
    const float* awi = (const float*)d_in[7];
    const float* abr = (const float*)d_in[8];
    const float* abi = (const float*)d_in[9];
    const float* par = (const float*)d_in[10];
    const float* pai = (const float*)d_in[11];
    float* out = (float*)d_out;

    // Workspace layout (floats): sRi[8192] | sIi[8192] | aux float4[8192]
    //                            | rowR[32768] | rowI[32768]
    float*  ws   = (float*)d_ws;
    float*  sRi  = ws;
    float*  sIi  = ws + 8192;
    float4* aux  = (float4*)(ws + 16384);
    float*  rowR = ws + 49152;
    float*  rowI = ws + 81920;

    k_scores  <<<dim3(2048), dim3(256), 0, stream>>>(Xr, Xi, awr, awi, sRi, sIi, aux);
    k_softmax <<<dim3(2048), dim3(256), 0, stream>>>(sRi, sIi, aux, abr, abi, par, pai);
    k_rowreduce<<<dim3(4096), dim3(256), 0, stream>>>(Lr, Li, sRi, sIi, aux,
                                                      abr, abi, par, pai, rowR, rowI);
    k_output  <<<dim3(512),  dim3(256), 0, stream>>>(Xr, Xi, wr, wi, rowR, rowI, out);
}